// Round 1
// baseline (643.883 us; speedup 1.0000x reference)
//
#include <hip/hip_runtime.h>

#define HH  512
#define WW  512
#define HPP 64
#define WPP 2048
#define BB  4
#define CC  64

// Mark masked (scatter-target) pixels. Duplicate-free by construction
// (n enumerates distinct pixels), same-value races are benign anyway.
__global__ __launch_bounds__(256) void mark_mask(
    const int* __restrict__ idx_y, const int* __restrict__ idx_x,
    unsigned char* __restrict__ mask, int N) {
    int n = blockIdx.x * 256 + threadIdx.x;
    if (n < N) mask[idx_y[n] * WW + idx_x[n]] = 1;
}

// Copy ref_feat -> out only where mask==0 (the small center disk).
// gridDim.y=8 splits the 256 (b,c) planes into chunks of 32 to cut tail latency.
__global__ __launch_bounds__(256) void fill_unmasked(
    const unsigned char* __restrict__ mask,
    const float* __restrict__ ref, float* __restrict__ out) {
    int p = blockIdx.x * 256 + threadIdx.x;
    if (p >= HH * WW) return;
    if (mask[p]) return;
    int bc0 = blockIdx.y * 32;
    #pragma unroll 8
    for (int k = 0; k < 32; ++k) {
        size_t off = (size_t)(bc0 + k) * (HH * WW) + p;
        out[off] = ref[off];
    }
}

// Fallback if ws is too small: plain full copy (float4).
__global__ __launch_bounds__(256) void copy_all(
    const float* __restrict__ ref, float* __restrict__ out) {
    size_t i = (size_t)blockIdx.x * 256 + threadIdx.x;   // in float4 units
    const float4* r4 = (const float4*)ref;
    float4* o4 = (float4*)out;
    o4[i] = r4[i];
}

// Bilinear sample (align_corners=True, zero padding) + scatter.
// Thread handles one n for 4 channels; writes are coalesced (consecutive n
// are row-major-consecutive cart pixels).
__global__ __launch_bounds__(256) void sample_scatter(
    const float* __restrict__ polar,
    const float* __restrict__ gx, const float* __restrict__ gy,
    const int* __restrict__ idx_y, const int* __restrict__ idx_x,
    float* __restrict__ out, int N) {
    int n = blockIdx.x * 256 + threadIdx.x;
    if (n >= N) return;
    int b  = blockIdx.z;
    int c0 = blockIdx.y * 4;

    float gxv = gx[n], gyv = gy[n];
    float ixf = (gxv + 1.0f) * ((WPP - 1) * 0.5f);
    float iyf = (gyv + 1.0f) * ((HPP - 1) * 0.5f);
    float x0f = floorf(ixf), y0f = floorf(iyf);
    float wx1 = ixf - x0f,  wy1 = iyf - y0f;
    float wx0 = 1.0f - wx1, wy0 = 1.0f - wy1;
    int x0 = (int)x0f, y0 = (int)y0f;
    int x1 = x0 + 1,   y1 = y0 + 1;

    bool vx0 = (x0 >= 0) & (x0 < WPP);
    bool vx1 = (x1 >= 0) & (x1 < WPP);
    bool vy0 = (y0 >= 0) & (y0 < HPP);
    bool vy1 = (y1 >= 0) & (y1 < HPP);
    int xc0 = min(max(x0, 0), WPP - 1);
    int xc1 = min(max(x1, 0), WPP - 1);
    int yc0 = min(max(y0, 0), HPP - 1);
    int yc1 = min(max(y1, 0), HPP - 1);
    float w00 = (vx0 && vy0) ? wx0 * wy0 : 0.0f;
    float w01 = (vx1 && vy0) ? wx1 * wy0 : 0.0f;
    float w10 = (vx0 && vy1) ? wx0 * wy1 : 0.0f;
    float w11 = (vx1 && vy1) ? wx1 * wy1 : 0.0f;

    size_t o00 = (size_t)yc0 * WPP + xc0;
    size_t o01 = (size_t)yc0 * WPP + xc1;
    size_t o10 = (size_t)yc1 * WPP + xc0;
    size_t o11 = (size_t)yc1 * WPP + xc1;

    int oy = idx_y[n], ox = idx_x[n];
    size_t outp = ((size_t)(b * CC + c0) * HH + oy) * WW + ox;
    const float* base = polar + (size_t)(b * CC + c0) * (HPP * WPP);

    #pragma unroll
    for (int k = 0; k < 4; ++k) {
        const float* p = base + (size_t)k * (HPP * WPP);
        float v = p[o00] * w00 + p[o01] * w01 + p[o10] * w10 + p[o11] * w11;
        out[outp + (size_t)k * (HH * WW)] = v;
    }
}

extern "C" void kernel_launch(void* const* d_in, const int* in_sizes, int n_in,
                              void* d_out, int out_size, void* d_ws, size_t ws_size,
                              hipStream_t stream) {
    const float* polar = (const float*)d_in[0];
    const float* ref   = (const float*)d_in[1];
    const float* gxp   = (const float*)d_in[2];
    const float* gyp   = (const float*)d_in[3];
    const int*   iyp   = (const int*)d_in[4];
    const int*   ixp   = (const int*)d_in[5];
    float* out = (float*)d_out;
    int N = in_sizes[2];

    if (ws_size >= (size_t)(HH * WW)) {
        unsigned char* mask = (unsigned char*)d_ws;
        hipMemsetAsync(mask, 0, HH * WW, stream);
        mark_mask<<<(N + 255) / 256, 256, 0, stream>>>(iyp, ixp, mask, N);
        fill_unmasked<<<dim3((HH * WW + 255) / 256, 8), 256, 0, stream>>>(mask, ref, out);
    } else {
        size_t n4 = (size_t)BB * CC * HH * WW / 4;
        copy_all<<<(unsigned)(n4 / 256), 256, 0, stream>>>(ref, out);
    }

    sample_scatter<<<dim3((N + 255) / 256, CC / 4, BB), 256, 0, stream>>>(
        polar, gxp, gyp, iyp, ixp, out, N);
}

// Round 2
// 629.387 us; speedup vs baseline: 1.0230x; 1.0230x over previous
//
#include <hip/hip_runtime.h>

#define HH  512
#define WW  512
#define HPP 64
#define WPP 2048
#define BB  4
#define CC  64

// Fill the center "drop" disk (pixels the scatter never writes) from ref_feat.
// Analytic recomputation of index_y <= 0, with +1e-3 margin: pixels in the
// margin band are also written by sample_scatter, which runs AFTER this kernel
// on the same stream, so any overlap is overwritten with the correct value.
// The disk (depth <= ~16.22px around center 255.5) fits in rows/cols 240..271.
__global__ __launch_bounds__(256) void fill_disk(
    const float* __restrict__ ref, float* __restrict__ out) {
    int t  = blockIdx.x * 256 + threadIdx.x;   // 0..1023 -> 32x32 box
    int bc = blockIdx.y;                       // 0..255 = b*C+c plane
    int r = 240 + (t >> 5);
    int c = 240 + (t & 31);
    float yyc = (float)r - 255.5f;
    float xxc = (float)c - 255.5f;
    float depth = sqrtf(yyc * yyc + xxc * xxc);
    // numpy: index_y = depth / (256*sqrt(2)) * 67 - 3
    float iyv = depth * (67.0f / 362.03867196751236f) - 3.0f;
    if (iyv <= 1e-3f) {
        size_t off = (size_t)bc * (HH * WW) + (size_t)r * WW + c;
        out[off] = ref[off];
    }
}

// Bilinear sample (align_corners=True, zero padding) + scatter.
// One thread per masked pixel n for one batch b; loops all 64 channels.
// Writes are coalesced (consecutive n = row-major-consecutive cart pixels);
// nontemporal stores keep the 256MB write stream from thrashing L2/L3 so
// polar lines stay resident for cross-pixel reuse.
__global__ __launch_bounds__(256) void sample_scatter(
    const float* __restrict__ polar,
    const float* __restrict__ gx, const float* __restrict__ gy,
    const int* __restrict__ idx_y, const int* __restrict__ idx_x,
    float* __restrict__ out, int N) {
    int n = blockIdx.x * 256 + threadIdx.x;
    if (n >= N) return;
    int b = blockIdx.y;

    float gxv = gx[n], gyv = gy[n];
    float ixf = (gxv + 1.0f) * ((WPP - 1) * 0.5f);
    float iyf = (gyv + 1.0f) * ((HPP - 1) * 0.5f);
    float x0f = floorf(ixf), y0f = floorf(iyf);
    float wx1 = ixf - x0f,  wy1 = iyf - y0f;
    float wx0 = 1.0f - wx1, wy0 = 1.0f - wy1;
    int x0 = (int)x0f, y0 = (int)y0f;
    int x1 = x0 + 1,   y1 = y0 + 1;

    bool vx0 = (x0 >= 0) & (x0 < WPP);
    bool vx1 = (x1 >= 0) & (x1 < WPP);
    bool vy0 = (y0 >= 0) & (y0 < HPP);
    bool vy1 = (y1 >= 0) & (y1 < HPP);
    int xc0 = min(max(x0, 0), WPP - 1);
    int xc1 = min(max(x1, 0), WPP - 1);
    int yc0 = min(max(y0, 0), HPP - 1);
    int yc1 = min(max(y1, 0), HPP - 1);
    float w00 = (vx0 && vy0) ? wx0 * wy0 : 0.0f;
    float w01 = (vx1 && vy0) ? wx1 * wy0 : 0.0f;
    float w10 = (vx0 && vy1) ? wx0 * wy1 : 0.0f;
    float w11 = (vx1 && vy1) ? wx1 * wy1 : 0.0f;

    int o00 = yc0 * WPP + xc0;
    int o01 = yc0 * WPP + xc1;
    int o10 = yc1 * WPP + xc0;
    int o11 = yc1 * WPP + xc1;

    int oy = idx_y[n], ox = idx_x[n];
    const float* p = polar + (size_t)b * CC * (HPP * WPP);
    float* o = out + (size_t)b * CC * (HH * WW) + (size_t)oy * WW + ox;

    #pragma unroll 8
    for (int c = 0; c < CC; ++c) {
        float v = p[o00] * w00 + p[o01] * w01 + p[o10] * w10 + p[o11] * w11;
        __builtin_nontemporal_store(v, o);
        p += HPP * WPP;
        o += HH * WW;
    }
}

extern "C" void kernel_launch(void* const* d_in, const int* in_sizes, int n_in,
                              void* d_out, int out_size, void* d_ws, size_t ws_size,
                              hipStream_t stream) {
    const float* polar = (const float*)d_in[0];
    const float* ref   = (const float*)d_in[1];
    const float* gxp   = (const float*)d_in[2];
    const float* gyp   = (const float*)d_in[3];
    const int*   iyp   = (const int*)d_in[4];
    const int*   ixp   = (const int*)d_in[5];
    float* out = (float*)d_out;
    int N = in_sizes[2];

    fill_disk<<<dim3(4, BB * CC), 256, 0, stream>>>(ref, out);
    sample_scatter<<<dim3((N + 255) / 256, BB), 256, 0, stream>>>(
        polar, gxp, gyp, iyp, ixp, out, N);
}